// Round 4
// baseline (630.456 us; speedup 1.0000x reference)
//
#include <hip/hip_runtime.h>
#include <hip/hip_bf16.h>

// FLASH/GAU block: B=4 N=4096 DIM=1024 QK=128 G=256, all GEMMs in TN form
// (A: MxK row-major, B: NxK row-major, K contiguous) via one templated bf16
// MFMA kernel: 128x128x64 tile (BK=64, 32KB LDS), 4 waves, 16x16x32 MFMA,
// global_load_lds width-16 staging, fused per-mode epilogues.
// Mode 1 (qk proj) is fused into mode 0 via B = [W_h^T | W_qk^T] (4224x1024).

typedef __attribute__((ext_vector_type(8))) short short8;
typedef __attribute__((ext_vector_type(4))) float f32x4;

#define BM 128
#define BN 128
#define BK 64

struct Aux {
  const float* b1;              // b_h (mode0) / b_out (mode6)
  const float* b2;              // b_qk (mode0 fused qk cols)
  const float* x;               // residual (mode6)
  const float* gamma;           // os_gamma (mode0 qk cols)
  const float* beta;            // os_beta
  const float* biastab;         // rel-pos table (mode2)
  const unsigned short* a2;     // mode3 tail A: lin_q (16384x128)
  const unsigned short* bkv;    // mode3 tail B: linkvT (4x2048x128)
  const unsigned short* gate;   // mode3: bf16 gate
  unsigned short* o16a;
  unsigned short* o16b;
  unsigned short* o16c;
  unsigned short* o16d;
  unsigned short* o16e;
  unsigned short* o16f;
  float* o32;
};

__device__ __forceinline__ float bf2f(unsigned short u) {
  union { float f; unsigned int i; } w; w.i = ((unsigned int)u) << 16; return w.f;
}
__device__ __forceinline__ unsigned short f2bf(float f) {
  union { float f; unsigned int i; } w; w.f = f;
  unsigned int x = w.i;
  return (unsigned short)((x + 0x7FFFu + ((x >> 16) & 1u)) >> 16);
}
__device__ __forceinline__ float silu_f(float z) { return z / (1.0f + __expf(-z)); }

// async global->LDS, 16B per lane; l must be the wave-uniform base
__device__ __forceinline__ void async_cp16(const unsigned short* g, unsigned short* l) {
  __builtin_amdgcn_global_load_lds(
      (const __attribute__((address_space(1))) void*)g,
      (__attribute__((address_space(3))) void*)l, 16, 0, 0);
}

__device__ __forceinline__ float block_sum(float v) {
  #pragma unroll
  for (int o = 32; o > 0; o >>= 1) v += __shfl_down(v, o, 64);
  __shared__ float sh[4];
  __syncthreads();
  if ((threadIdx.x & 63) == 0) sh[threadIdx.x >> 6] = v;
  __syncthreads();
  return sh[0] + sh[1] + sh[2] + sh[3];
}

// LayerNorm over DIM=1024, one block per row, output bf16.
__global__ __launch_bounds__(256) void ln_k(const float* __restrict__ x,
                                            const float* __restrict__ g,
                                            const float* __restrict__ b,
                                            unsigned short* __restrict__ out) {
  const int row = blockIdx.x;
  const int tid = threadIdx.x;
  const float4 xv = ((const float4*)(x + (size_t)row * 1024))[tid];
  float s = xv.x + xv.y + xv.z + xv.w;
  s = block_sum(s);
  const float mu = s * (1.0f / 1024.0f);
  const float d0 = xv.x - mu, d1 = xv.y - mu, d2 = xv.z - mu, d3 = xv.w - mu;
  float q = d0 * d0 + d1 * d1 + d2 * d2 + d3 * d3;
  q = block_sum(q);
  const float rstd = rsqrtf(q * (1.0f / 1024.0f) + 1e-5f);
  const float4 gv = ((const float4*)g)[tid];
  const float4 bv = ((const float4*)b)[tid];
  unsigned short* o = out + (size_t)row * 1024 + tid * 4;
  o[0] = f2bf(d0 * rstd * gv.x + bv.x);
  o[1] = f2bf(d1 * rstd * gv.y + bv.y);
  o[2] = f2bf(d2 * rstd * gv.z + bv.z);
  o[3] = f2bf(d3 * rstd * gv.w + bv.w);
}

// transpose-cast: in[K][N] fp32 -> out[N][K] bf16, 64x64 LDS tiles
__global__ __launch_bounds__(256) void tc_k(const float* __restrict__ in,
                                            unsigned short* __restrict__ out,
                                            int K, int N) {
  __shared__ unsigned short L[64][65];
  const int t = threadIdx.x;
  const int k0 = blockIdx.y * 64, n0 = blockIdx.x * 64;
  const int r = t >> 4, c4 = (t & 15) * 4;
  #pragma unroll
  for (int rr = 0; rr < 4; ++rr) {
    const int kk = rr * 16 + r;
    const float4 f = ((const float4*)(in + (size_t)(k0 + kk) * N + n0))[t & 15];
    L[kk][c4 + 0] = f2bf(f.x); L[kk][c4 + 1] = f2bf(f.y);
    L[kk][c4 + 2] = f2bf(f.z); L[kk][c4 + 3] = f2bf(f.w);
  }
  __syncthreads();
  #pragma unroll
  for (int rr = 0; rr < 4; ++rr) {
    const int nn = rr * 16 + r;
    ushort4 u;
    u.x = L[c4 + 0][nn]; u.y = L[c4 + 1][nn];
    u.z = L[c4 + 2][nn]; u.w = L[c4 + 3][nn];
    ((ushort4*)(out + (size_t)(n0 + nn) * K + k0))[t & 15] = u;
  }
}

// rel-pos bias table: tab[d + 255] for d = j - i in [-255, 255]
__global__ void bias_k(const float* __restrict__ rel, float* __restrict__ tab) {
  int idx = blockIdx.x * 256 + threadIdx.x;
  if (idx >= 511) return;
  int d = idx - 255;       // j - i
  int n = -d;              // i - j
  int ret = (n < 0) ? 16 : 0;
  int a = (n < 0) ? -n : n;
  int bucket;
  if (a < 8) {
    bucket = ret + a;
  } else {
    float t = __logf((float)a * 0.125f) / 2.7725887298583984f * 8.0f;
    int vl = 8 + (int)t;
    if (vl > 15) vl = 15;
    bucket = ret + vl;
  }
  tab[idx] = rel[bucket] * 11.313708498984761f;  // * sqrt(QK)
}

// reduce 4 split-K partials of pkvT[b][s][e][d], scale 1/N, cast -> linkvT[b][e][d]
__global__ void kvred_k(const float* __restrict__ pkv, unsigned short* __restrict__ linkvT) {
  int i4 = blockIdx.x * 256 + threadIdx.x;   // < 262144 (float4 units)
  const int b = i4 >> 16, rem = i4 & 65535;
  const float4* p = (const float4*)(pkv + (size_t)b * 1048576) + rem;
  const float4 p0 = p[0], p1 = p[65536], p2 = p[131072], p3 = p[196608];
  ushort4 u;
  u.x = f2bf((p0.x + p1.x + p2.x + p3.x) * (1.0f / 4096.0f));
  u.y = f2bf((p0.y + p1.y + p2.y + p3.y) * (1.0f / 4096.0f));
  u.z = f2bf((p0.z + p1.z + p2.z + p3.z) * (1.0f / 4096.0f));
  u.w = f2bf((p0.w + p1.w + p2.w + p3.w) * (1.0f / 4096.0f));
  ((ushort4*)(linkvT + (size_t)b * 262144))[rem] = u;
}

// TN bf16 MFMA GEMM: C = A(MxK) @ B(NxK)^T, K contiguous in both.
// MODE 0: hid+qk M=16384 N=4224 K=1024; epi silu: col<2048 -> vT, <4096 -> gate,
//         else qk 4-head writes (qq/lq/qkk row-major, linkT[b][d][t])
// MODE 2: sim   per-group M=N=256 K=128; epi /G +bias, relu^2 -> attn
// MODE 3: quad+lin per-group M=256 N=2048 K=256(attn@vT)+128(lq@linkvT); epi *gate
// MODE 4: lin_kv split-K x4 per batch M=128(d) N=2048(e) K=1024; epi fp32 pkvT[e][d]
// MODE 6: final M=16384 N=1024 K=2048; epi +b_out +x -> fp32 out
template<int MODE>
__global__ __launch_bounds__(256, 2) void gemm_k(
    const unsigned short* __restrict__ Ag,
    const unsigned short* __restrict__ Bg,
    int lda, int ldb, int kiters, Aux aux)
{
  __shared__ unsigned short As[BM * BK];
  __shared__ unsigned short Bs[BN * BK];

  const int tid  = threadIdx.x;
  const int lane = tid & 63;
  const int wave = tid >> 6;
  const int quad = lane >> 4;
  const int l16  = lane & 15;
  const int wm   = (wave >> 1) * 64;
  const int wn   = (wave & 1) * 64;
  const int bz   = blockIdx.z;
  const int bm   = blockIdx.y * BM;
  const int bn   = blockIdx.x * BN;

  const unsigned short* A = Ag;
  const unsigned short* B = Bg;
  if constexpr (MODE == 2) { A += (size_t)bz * 32768;  B += (size_t)bz * 32768; }
  if constexpr (MODE == 3) { A += (size_t)bz * 65536;                       // attn group
                             B += (size_t)(bz >> 4) * 8388608 + (size_t)(bz & 15) * 256; } // vT + g*256
  if constexpr (MODE == 4) { const int b = bz >> 2, s = bz & 3;
                             A += (size_t)b * 524288 + (size_t)s * 1024;    // linkT cols s*1024..
                             B += (size_t)b * 8388608 + (size_t)s * 1024; } // vT cols s*1024..

  const unsigned short* A2 = nullptr;
  const unsigned short* B2 = nullptr;
  if constexpr (MODE == 3) {
    A2 = aux.a2 + (size_t)bz * 32768;            // lq group (256x128)
    B2 = aux.bkv + (size_t)(bz >> 4) * 262144;   // linkvT batch (2048x128)
  }

  // staging: per issue, wave w fills 8 rows x 128B; lane l -> row l>>3, col (l&7)*8
  const int srow = wave * 8 + (lane >> 3);
  const int scol = (lane & 7) * 8;
  unsigned short* lA = As + wave * 512;     // wave-uniform LDS bases
  unsigned short* lB = Bs + wave * 512;

  const f32x4 zero = {0.f, 0.f, 0.f, 0.f};
  f32x4 acc[4][4];
  #pragma unroll
  for (int i = 0; i < 4; ++i)
    #pragma unroll
    for (int j = 0; j < 4; ++j) acc[i][j] = zero;

  for (int kt = 0; kt < kiters; ++kt) {
    const unsigned short* pa = A;
    const unsigned short* pb = B;
    int la = lda, lb = ldb, kk = kt * BK;
    if constexpr (MODE == 3) {
      if (kt >= 4) { pa = A2; pb = B2; la = 128; lb = 128; kk -= 256; }
    }

    __syncthreads();  // prior iteration's LDS reads complete
    #pragma unroll
    for (int i = 0; i < 4; ++i) {
      async_cp16(pa + (size_t)(bm + i * 32 + srow) * la + kk + scol, lA + i * 2048);
      async_cp16(pb + (size_t)(bn + i * 32 + srow) * lb + kk + scol, lB + i * 2048);
    }
    __syncthreads();  // drains vmcnt (compiler) -> staged data visible

    #pragma unroll
    for (int kh = 0; kh < 2; ++kh) {
      short8 af[4], bfv[4];
      #pragma unroll
      for (int i = 0; i < 4; ++i)
        af[i] = *reinterpret_cast<const short8*>(As + (wm + i * 16 + l16) * BK + kh * 32 + quad * 8);
      #pragma unroll
      for (int j = 0; j < 4; ++j)
        bfv[j] = *reinterpret_cast<const short8*>(Bs + (wn + j * 16 + l16) * BK + kh * 32 + quad * 8);
      #pragma unroll
      for (int i = 0; i < 4; ++i)
        #pragma unroll
        for (int j = 0; j < 4; ++j)
          acc[i][j] = __builtin_amdgcn_mfma_f32_16x16x32_bf16(af[i], bfv[j], acc[i][j], 0, 0, 0);
    }
  }

  // epilogue: D[row=quad*4+r][col=l16] per 16x16 tile
  #pragma unroll
  for (int i = 0; i < 4; ++i) {
    #pragma unroll
    for (int j = 0; j < 4; ++j) {
      const int row0 = bm + wm + i * 16 + quad * 4;
      const int col  = bn + wn + j * 16 + l16;
      if constexpr (MODE == 0) {
        if (col < 4096) {          // hid: v / gate (branch uniform per block)
          const float bb = aux.b1[col];
          float s[4];
          #pragma unroll
          for (int r = 0; r < 4; ++r) s[r] = silu_f(acc[i][j][r] + bb);
          if (col < 2048) {        // vT[b][e][t]
            const int b = row0 >> 12, t = row0 & 4095;
            ushort4 u; u.x = f2bf(s[0]); u.y = f2bf(s[1]); u.z = f2bf(s[2]); u.w = f2bf(s[3]);
            *(ushort4*)(aux.o16a + (size_t)b * 8388608 + (size_t)col * 4096 + t) = u;
          } else {                 // gate row-major
            #pragma unroll
            for (int r = 0; r < 4; ++r)
              aux.o16b[(size_t)(row0 + r) * 2048 + (col - 2048)] = f2bf(s[r]);
          }
        } else {                   // fused qk projection, cq in [0,128)
          const int cq = col - 4096;
          const float bb = aux.b2[cq];
          float s[4];
          #pragma unroll
          for (int r = 0; r < 4; ++r) s[r] = silu_f(acc[i][j][r] + bb);
          #pragma unroll
          for (int r = 0; r < 4; ++r) {
            const size_t idx = (size_t)(row0 + r) * 128 + cq;
            aux.o16c[idx] = f2bf(s[r] * aux.gamma[cq]       + aux.beta[cq]);        // quad_q
            aux.o16d[idx] = f2bf(s[r] * aux.gamma[128 + cq] + aux.beta[128 + cq]);  // lin_q
            aux.o16e[idx] = f2bf(s[r] * aux.gamma[256 + cq] + aux.beta[256 + cq]);  // quad_k
          }
          const int b = row0 >> 12, t = row0 & 4095;                                // lin_k^T
          const float g4 = aux.gamma[384 + cq], b4 = aux.beta[384 + cq];
          ushort4 u;
          u.x = f2bf(s[0] * g4 + b4); u.y = f2bf(s[1] * g4 + b4);
          u.z = f2bf(s[2] * g4 + b4); u.w = f2bf(s[3] * g4 + b4);
          *(ushort4*)(aux.o16f + (size_t)b * 524288 + (size_t)cq * 4096 + t) = u;
        }
      } else if constexpr (MODE == 2) {
        #pragma unroll
        for (int r = 0; r < 4; ++r) {
          float s = acc[i][j][r] * (1.0f / 256.0f) + aux.biastab[col - (row0 + r) + 255];
          s = fmaxf(s, 0.0f);
          aux.o16a[(size_t)bz * 65536 + (size_t)(row0 + r) * 256 + col] = f2bf(s * s);
        }
      } else if constexpr (MODE == 3) {
        #pragma unroll
        for (int r = 0; r < 4; ++r) {
          const size_t idx = ((size_t)bz * 256 + row0 + r) * 2048 + col;
          aux.o16a[idx] = f2bf(acc[i][j][r] * bf2f(aux.gate[idx]));
        }
      } else if constexpr (MODE == 4) {
        float4 u; u.x = acc[i][j][0]; u.y = acc[i][j][1]; u.z = acc[i][j][2]; u.w = acc[i][j][3];
        *(float4*)(aux.o32 + (size_t)bz * 262144 + (size_t)col * 128 + row0) = u;
      } else if constexpr (MODE == 6) {
        #pragma unroll
        for (int r = 0; r < 4; ++r) {
          const size_t idx = (size_t)(row0 + r) * 1024 + col;
          aux.o32[idx] = acc[i][j][r] + aux.b1[col] + aux.x[idx];
        }
      }
    }
  }
}

extern "C" void kernel_launch(void* const* d_in, const int* in_sizes, int n_in,
                              void* d_out, int out_size, void* d_ws, size_t ws_size,
                              hipStream_t stream) {
  (void)in_sizes; (void)n_in; (void)out_size; (void)ws_size;
  const float* x     = (const float*)d_in[0];
  const float* ln_g  = (const float*)d_in[1];
  const float* ln_b  = (const float*)d_in[2];
  const float* W_h   = (const float*)d_in[3];
  const float* b_h   = (const float*)d_in[4];
  const float* W_qk  = (const float*)d_in[5];
  const float* b_qk  = (const float*)d_in[6];
  const float* osg   = (const float*)d_in[7];
  const float* osb   = (const float*)d_in[8];
  const float* rel   = (const float*)d_in[9];
  const float* W_out = (const float*)d_in[10];
  const float* b_out = (const float*)d_in[11];
  float* out = (float*)d_out;

  char* w = (char*)d_ws;
  size_t off = 0;
  auto alloc = [&](size_t bytes) { char* p = w + off; off += (bytes + 255) & ~(size_t)255; return p; };

  // ---- arena R (all dead before mode 3 writes `gated`, which aliases R) ----
  unsigned short* normed = (unsigned short*)alloc(16384ull * 1024 * 2);   // 32M, dead after mode0
  unsigned short* whqkT  = (unsigned short*)alloc(4224ull * 1024 * 2);    // 8.25M, dead after mode0
  unsigned short* qq     = (unsigned short*)alloc(16384ull * 128 * 2);    //  4M, dead after mode2
  unsigned short* qkk    = (unsigned short*)alloc(16384ull * 128 * 2);    //  4M, dead after mode2
  unsigned short* linkT  = (unsigned short*)alloc(4ull * 128 * 4096 * 2); //  4M, dead after mode4
  float*          pkvT   = (float*)alloc(16ull * 2048 * 128 * 4);         // 16M, dead after kvred
  // ---- live-through buffers ----
  unsigned short* woutT  = (unsigned short*)alloc(1024ull * 2048 * 2);
  unsigned short* vT     = (unsigned short*)alloc(4ull * 2048 * 4096 * 2); // 64M
  unsigned short* gate   = (unsigned short*)alloc(16384ull * 2048 * 2);    // 64M
  unsigned short* lq     = (unsigned short*)alloc(16384ull * 128 * 2);
  unsigned short* attn   = (unsigned short*)alloc(64ull * 256 * 256 * 2);  //  8M
  unsigned short* linkvT = (unsigned short*)alloc(4ull * 2048 * 128 * 2);
  float*          btab   = (float*)alloc(511 * 4);
  unsigned short* gated  = (unsigned short*)w;  // alias arena R (64M needed, ~68M there)

  tc_k<<<dim3(64, 16), 256, 0, stream>>>(W_h,   whqkT,              1024, 4096);
  tc_k<<<dim3(2, 16),  256, 0, stream>>>(W_qk,  whqkT + 4096 * 1024, 1024, 128);
  tc_k<<<dim3(16, 32), 256, 0, stream>>>(W_out, woutT, 2048, 1024);
  bias_k<<<2, 256, 0, stream>>>(rel, btab);
  ln_k<<<16384, 256, 0, stream>>>(x, ln_g, ln_b, normed);

  Aux a0{}; a0.b1 = b_h; a0.b2 = b_qk; a0.gamma = osg; a0.beta = osb;
  a0.o16a = vT; a0.o16b = gate; a0.o16c = qq; a0.o16d = lq; a0.o16e = qkk; a0.o16f = linkT;
  gemm_k<0><<<dim3(33, 128, 1), 256, 0, stream>>>(normed, whqkT, 1024, 1024, 16, a0);

  Aux a2x{}; a2x.biastab = btab; a2x.o16a = attn;
  gemm_k<2><<<dim3(2, 2, 64), 256, 0, stream>>>(qq, qkk, 128, 128, 2, a2x);

  Aux a4{}; a4.o32 = pkvT;
  gemm_k<4><<<dim3(16, 1, 16), 256, 0, stream>>>(linkT, vT, 4096, 4096, 4, a4);

  kvred_k<<<1024, 256, 0, stream>>>(pkvT, linkvT);

  Aux a3{}; a3.a2 = lq; a3.bkv = linkvT; a3.gate = gate; a3.o16a = gated;
  gemm_k<3><<<dim3(16, 2, 64), 256, 0, stream>>>(attn, vT, 256, 4096, 6, a3);

  Aux a6{}; a6.b1 = b_out; a6.x = x; a6.o32 = out;
  gemm_k<6><<<dim3(8, 128, 1), 256, 0, stream>>>(gated, woutT, 2048, 2048, 32, a6);
}